// Round 1
// baseline (3069.604 us; speedup 1.0000x reference)
//
#include <hip/hip_runtime.h>
#include <hip/hip_bf16.h>

// Problem constants
#define LQ   4096
#define DMOD 768
#define IMGD 1408
#define TT   2
#define MM   6
#define LL   3
#define PP   4
#define DH   128            // DMOD / MM
#define STOT 25039          // 28^3 + 14^3 + 7^3
#define OFFC 432            // M*T*L*P*3
#define AWC  144            // M*T*L*P

// ---------------------------------------------------------------------------
// Generic tiled fp32 GEMM: C(MxN) = A(MxK) @ B(KxN) + bias(N)
// 64x64 block tile, 16 k-tile, 256 threads, 4x4 per-thread microtile.
// Requires K % 16 == 0 (true for K=1408 and K=768).
// ---------------------------------------------------------------------------
#define BM 64
#define BN 64
#define BK 16

__global__ __launch_bounds__(256) void gemm_f32(
    const float* __restrict__ A, const float* __restrict__ B,
    const float* __restrict__ bias, float* __restrict__ C,
    int M, int N, int K)
{
    __shared__ float As[BK][BM + 1];
    __shared__ float Bs[BK][BN + 1];

    const int tid = threadIdx.x;
    const int tx  = tid & 15;   // 0..15 -> col group
    const int ty  = tid >> 4;   // 0..15 -> row group
    const int row0 = blockIdx.y * BM;
    const int col0 = blockIdx.x * BN;

    float c[4][4] = {};

    for (int kt = 0; kt < K; kt += BK) {
        // --- load A tile (64 rows x 16 k), store transposed As[k][m]
        {
            int m  = tid >> 2;          // 0..63
            int kk = (tid & 3) * 4;     // 0,4,8,12
            int gm = row0 + m;
            float4 av = make_float4(0.f, 0.f, 0.f, 0.f);
            if (gm < M) {
                const float* ap = A + (size_t)gm * K + kt + kk;  // K%16==0 -> in range
                av.x = ap[0]; av.y = ap[1]; av.z = ap[2]; av.w = ap[3];
            }
            As[kk + 0][m] = av.x; As[kk + 1][m] = av.y;
            As[kk + 2][m] = av.z; As[kk + 3][m] = av.w;
        }
        // --- load B tile (16 k x 64 cols), Bs[k][n]
        {
            int kk = tid >> 4;          // 0..15
            int n  = (tid & 15) * 4;    // 0..60
            int gn = col0 + n;
            const float* bp = B + (size_t)(kt + kk) * N + gn;
            float4 bv = make_float4(0.f, 0.f, 0.f, 0.f);
            if (gn + 3 < N) {
                bv.x = bp[0]; bv.y = bp[1]; bv.z = bp[2]; bv.w = bp[3];
            } else {
                if (gn + 0 < N) bv.x = bp[0];
                if (gn + 1 < N) bv.y = bp[1];
                if (gn + 2 < N) bv.z = bp[2];
                if (gn + 3 < N) bv.w = bp[3];
            }
            Bs[kk][n + 0] = bv.x; Bs[kk][n + 1] = bv.y;
            Bs[kk][n + 2] = bv.z; Bs[kk][n + 3] = bv.w;
        }
        __syncthreads();

        #pragma unroll
        for (int k = 0; k < BK; ++k) {
            float a[4], b[4];
            #pragma unroll
            for (int i = 0; i < 4; ++i) a[i] = As[k][ty * 4 + i];
            #pragma unroll
            for (int j = 0; j < 4; ++j) b[j] = Bs[k][tx * 4 + j];
            #pragma unroll
            for (int i = 0; i < 4; ++i)
                #pragma unroll
                for (int j = 0; j < 4; ++j)
                    c[i][j] += a[i] * b[j];
        }
        __syncthreads();
    }

    // --- store with bias
    #pragma unroll
    for (int i = 0; i < 4; ++i) {
        int gm = row0 + ty * 4 + i;
        if (gm >= M) continue;
        #pragma unroll
        for (int j = 0; j < 4; ++j) {
            int gn = col0 + tx * 4 + j;
            if (gn < N) C[(size_t)gm * N + gn] = c[i][j] + bias[gn];
        }
    }
}

// ---------------------------------------------------------------------------
// Fused softmax + trilinear sampling + head-wise accumulation.
// One block per (q, m); 128 threads = one per channel d.
// attn[q*768 + m*128 + d] = sum_{t,l,p} aw * trilinear(v_level_l, loc)
// ---------------------------------------------------------------------------
__global__ __launch_bounds__(128) void sample_kernel(
    const float* __restrict__ refp,   // (LQ,3)
    const float* __restrict__ offb,   // (LQ,432)
    const float* __restrict__ alog,   // (LQ,144) logits (pre-softmax)
    const float* __restrict__ vbuf,   // (T, STOT, 768)
    float* __restrict__ attn)         // (LQ, 768)
{
    const int q = blockIdx.x;
    const int m = blockIdx.y;
    const int d = threadIdx.x;

    __shared__ float s_off[72];
    __shared__ float s_aw[24];
    __shared__ float s_ref[3];

    if (d < 72) s_off[d] = offb[(size_t)q * OFFC + m * 72 + d];
    if (d < 24) s_aw[d]  = alog[(size_t)q * AWC + m * 24 + d];
    if (d < 3)  s_ref[d] = refp[(size_t)q * 3 + d];
    __syncthreads();

    if (d == 0) {
        float mx = s_aw[0];
        #pragma unroll
        for (int i = 1; i < 24; ++i) mx = fmaxf(mx, s_aw[i]);
        float sum = 0.f;
        #pragma unroll
        for (int i = 0; i < 24; ++i) { float e = expf(s_aw[i] - mx); s_aw[i] = e; sum += e; }
        float inv = 1.f / sum;
        #pragma unroll
        for (int i = 0; i < 24; ++i) s_aw[i] *= inv;
    }
    __syncthreads();

    const int   DLS[3]   = {28, 14, 7};
    const int   START[3] = {0, 21952, 24696};

    float acc = 0.f;

    #pragma unroll
    for (int t = 0; t < TT; ++t) {
        #pragma unroll
        for (int l = 0; l < LL; ++l) {
            const int   Dl = DLS[l];
            const float fD = (float)Dl;
            const float* vb = vbuf + ((size_t)t * STOT + START[l]) * DMOD + m * DH + d;
            #pragma unroll
            for (int p = 0; p < PP; ++p) {
                const int o = t * 36 + l * 12 + p * 3;
                const float aww = s_aw[t * 12 + l * 4 + p];
                // loc = ref + off/norm ; x = loc*W - 0.5  (norm == W == H == D per level)
                float x = s_ref[0] * fD + s_off[o + 0] - 0.5f;
                float y = s_ref[1] * fD + s_off[o + 1] - 0.5f;
                float z = s_ref[2] * fD + s_off[o + 2] - 0.5f;
                float xf = floorf(x), yf = floorf(y), zf = floorf(z);
                float fx = x - xf, fy = y - yf, fz = z - zf;
                int x0 = (int)xf, y0 = (int)yf, z0 = (int)zf;
                #pragma unroll
                for (int cc = 0; cc < 8; ++cc) {
                    int dx = cc & 1, dy = (cc >> 1) & 1, dz = cc >> 2;
                    int xi = x0 + dx, yi = y0 + dy, zi = z0 + dz;
                    if (xi < 0 || xi >= Dl || yi < 0 || yi >= Dl || zi < 0 || zi >= Dl) continue;
                    float w = (dx ? fx : 1.f - fx) * (dy ? fy : 1.f - fy) * (dz ? fz : 1.f - fz);
                    acc += (aww * w) * vb[(size_t)((zi * Dl + yi) * Dl + xi) * DMOD];
                }
            }
        }
    }

    attn[(size_t)q * DMOD + m * DH + d] = acc;
}

// ---------------------------------------------------------------------------
extern "C" void kernel_launch(void* const* d_in, const int* in_sizes, int n_in,
                              void* d_out, int out_size, void* d_ws, size_t ws_size,
                              hipStream_t stream) {
    const float* query = (const float*)d_in[0];   // (1, 4096, 768)
    const float* refp  = (const float*)d_in[1];   // (1, 4096, 3)
    const float* value = (const float*)d_in[2];   // (1, 2, 25039, 1408)
    const float* Wv    = (const float*)d_in[3];   // (1408, 768)
    const float* bv    = (const float*)d_in[4];   // (768,)
    const float* Woff  = (const float*)d_in[5];   // (768, 432)
    const float* boff  = (const float*)d_in[6];   // (432,)
    const float* Wa    = (const float*)d_in[7];   // (768, 144)
    const float* ba    = (const float*)d_in[8];   // (144,)
    const float* Wo    = (const float*)d_in[9];   // (768, 768)
    const float* bo    = (const float*)d_in[10];  // (768,)
    float* out = (float*)d_out;                   // (1, 4096, 768)

    // workspace carve-up (floats)
    float* vbuf = (float*)d_ws;                         // 2*25039*768 = 38,459,904
    float* offb = vbuf + (size_t)TT * STOT * DMOD;      // 4096*432   =  1,769,472
    float* alog = offb + (size_t)LQ * OFFC;             // 4096*144   =    589,824
    float* attn = alog + (size_t)LQ * AWC;              // 4096*768   =  3,145,728

    // G1: v = value @ Wv + bv     (50078 x 768, K=1408)
    {
        int M = TT * STOT, N = DMOD, K = IMGD;
        dim3 grid((N + BN - 1) / BN, (M + BM - 1) / BM);
        gemm_f32<<<grid, 256, 0, stream>>>(value, Wv, bv, vbuf, M, N, K);
    }
    // G2a: off = query @ Woff + boff   (4096 x 432, K=768)
    {
        int M = LQ, N = OFFC, K = DMOD;
        dim3 grid((N + BN - 1) / BN, (M + BM - 1) / BM);
        gemm_f32<<<grid, 256, 0, stream>>>(query, Woff, boff, offb, M, N, K);
    }
    // G2b: alog = query @ Wa + ba      (4096 x 144, K=768)
    {
        int M = LQ, N = AWC, K = DMOD;
        dim3 grid((N + BN - 1) / BN, (M + BM - 1) / BM);
        gemm_f32<<<grid, 256, 0, stream>>>(query, Wa, ba, alog, M, N, K);
    }
    // sampling + softmax + head accumulation
    {
        dim3 grid(LQ, MM);
        sample_kernel<<<grid, DH, 0, stream>>>(refp, offb, alog, vbuf, attn);
    }
    // G3: out = attn @ Wo + bo         (4096 x 768, K=768)
    {
        int M = LQ, N = DMOD, K = DMOD;
        dim3 grid((N + BN - 1) / BN, (M + BM - 1) / BM);
        gemm_f32<<<grid, 256, 0, stream>>>(attn, Wo, bo, out, M, N, K);
    }
}

// Round 2
// 1349.211 us; speedup vs baseline: 2.2751x; 2.2751x over previous
//
#include <hip/hip_runtime.h>
#include <hip/hip_bf16.h>

// Problem constants
#define LQ   4096
#define DMOD 768
#define IMGD 1408
#define TT   2
#define MM   6
#define LL   3
#define PP   4
#define DH   128            // DMOD / MM
#define STOT 25039          // 28^3 + 14^3 + 7^3
#define OFFC 432            // M*T*L*P*3
#define AWC  144            // M*T*L*P

typedef __attribute__((ext_vector_type(8))) __bf16 bf16x8;
typedef __attribute__((ext_vector_type(4))) float  f32x4;

// ---------------------------------------------------------------------------
// Prep: WT[n][k] = (bf16) W[k][n]   (tiled transpose + convert)
// ---------------------------------------------------------------------------
__global__ __launch_bounds__(256) void cvt_transpose(
    const float* __restrict__ W, __bf16* __restrict__ WT, int K, int N)
{
    __shared__ float tile[32][33];
    const int k0 = blockIdx.x * 32, n0 = blockIdx.y * 32;
    const int c = threadIdx.x & 31, r8 = threadIdx.x >> 5;   // 8 rows/pass
    #pragma unroll
    for (int i = 0; i < 4; ++i) {
        int r = r8 + i * 8;
        int k = k0 + r, n = n0 + c;
        tile[r][c] = (k < K && n < N) ? W[(size_t)k * N + n] : 0.f;
    }
    __syncthreads();
    #pragma unroll
    for (int i = 0; i < 4; ++i) {
        int r = r8 + i * 8;
        int n = n0 + r, k = k0 + c;
        if (n < N && k < K) WT[(size_t)n * K + k] = (__bf16)tile[c][r];
    }
}

// ---------------------------------------------------------------------------
// bf16 MFMA GEMM: C(MxN) = A_f32(MxK) @ BT_bf16(NxK)^T + bias
// 128x128 block tile, BK=32, 256 threads (4 waves), wave tile 64x64.
// A converted fp32->bf16 during staging. K % 32 == 0 required.
// LDS layout [kc][row][8] -> all ds_read/ds_write are 16B-aligned b128.
// ---------------------------------------------------------------------------
__global__ __launch_bounds__(256) void gemm_bf16_mfma(
    const float* __restrict__ A, const __bf16* __restrict__ BT,
    const float* __restrict__ bias, float* __restrict__ C,
    int M, int N, int K)
{
    __shared__ __bf16 As[4][128][8];   // 8 KB
    __shared__ __bf16 Bs[4][128][8];   // 8 KB

    const int tid  = threadIdx.x;
    const int lane = tid & 63;
    const int wave = tid >> 6;
    const int wm = (wave & 1) * 64;
    const int wn = (wave >> 1) * 64;
    const int row0 = blockIdx.y * 128;
    const int col0 = blockIdx.x * 128;

    // staging mapping: thread -> (row, 16-wide k-halftile)
    const int sr  = tid >> 1;          // 0..127
    const int kk0 = (tid & 1) * 16;    // 0 or 16
    const int kc0 = kk0 >> 3;          // 0 or 2

    // frag mapping
    const int fr = lane & 15;
    const int kc = lane >> 4;

    f32x4 acc[4][4] = {};

    for (int kt = 0; kt < K; kt += 32) {
        // ---- stage A (128 rows x 32 k), fp32 -> bf16
        {
            const int gm = row0 + sr;
            float f[16];
            if (gm < M) {
                const float4* ap = (const float4*)(A + (size_t)gm * K + kt + kk0);
                #pragma unroll
                for (int i = 0; i < 4; ++i) {
                    float4 v = ap[i];
                    f[i*4+0] = v.x; f[i*4+1] = v.y; f[i*4+2] = v.z; f[i*4+3] = v.w;
                }
            } else {
                #pragma unroll
                for (int i = 0; i < 16; ++i) f[i] = 0.f;
            }
            bf16x8 v0, v1;
            #pragma unroll
            for (int i = 0; i < 8; ++i) { v0[i] = (__bf16)f[i]; v1[i] = (__bf16)f[i+8]; }
            *(bf16x8*)&As[kc0    ][sr][0] = v0;
            *(bf16x8*)&As[kc0 + 1][sr][0] = v1;
        }
        // ---- stage B (128 n x 32 k) from BT[n][k] (already bf16)
        {
            const int gn = col0 + sr;
            bf16x8 v0 = {}, v1 = {};
            if (gn < N) {
                const bf16x8* bp = (const bf16x8*)(BT + (size_t)gn * K + kt + kk0);
                v0 = bp[0]; v1 = bp[1];
            }
            *(bf16x8*)&Bs[kc0    ][sr][0] = v0;
            *(bf16x8*)&Bs[kc0 + 1][sr][0] = v1;
        }
        __syncthreads();

        // ---- MFMA: 4x4 16x16 tiles per wave
        bf16x8 a[4], b[4];
        #pragma unroll
        for (int mt = 0; mt < 4; ++mt) a[mt] = *(bf16x8*)&As[kc][wm + mt*16 + fr][0];
        #pragma unroll
        for (int nt = 0; nt < 4; ++nt) b[nt] = *(bf16x8*)&Bs[kc][wn + nt*16 + fr][0];
        #pragma unroll
        for (int mt = 0; mt < 4; ++mt)
            #pragma unroll
            for (int nt = 0; nt < 4; ++nt)
                acc[mt][nt] = __builtin_amdgcn_mfma_f32_16x16x32_bf16(
                    a[mt], b[nt], acc[mt][nt], 0, 0, 0);
        __syncthreads();
    }

    // ---- epilogue: C/D layout col=lane&15, row=(lane>>4)*4+reg
    const int col  = lane & 15;
    const int rq   = (lane >> 4) * 4;
    #pragma unroll
    for (int mt = 0; mt < 4; ++mt) {
        #pragma unroll
        for (int r = 0; r < 4; ++r) {
            const int gm = row0 + wm + mt*16 + rq + r;
            if (gm >= M) continue;
            #pragma unroll
            for (int nt = 0; nt < 4; ++nt) {
                const int gn = col0 + wn + nt*16 + col;
                if (gn < N) C[(size_t)gm * N + gn] = acc[mt][nt][r] + bias[gn];
            }
        }
    }
}

// ---------------------------------------------------------------------------
// fp32 tiled GEMM (kept for the small projections)
// ---------------------------------------------------------------------------
#define BM 64
#define BN 64
#define BK 16

__global__ __launch_bounds__(256) void gemm_f32(
    const float* __restrict__ A, const float* __restrict__ B,
    const float* __restrict__ bias, float* __restrict__ C,
    int M, int N, int K)
{
    __shared__ float As[BK][BM + 1];
    __shared__ float Bs[BK][BN + 1];

    const int tid = threadIdx.x;
    const int tx  = tid & 15;
    const int ty  = tid >> 4;
    const int row0 = blockIdx.y * BM;
    const int col0 = blockIdx.x * BN;

    float c[4][4] = {};

    for (int kt = 0; kt < K; kt += BK) {
        {
            int m  = tid >> 2;
            int kk = (tid & 3) * 4;
            int gm = row0 + m;
            float4 av = make_float4(0.f, 0.f, 0.f, 0.f);
            if (gm < M) {
                const float* ap = A + (size_t)gm * K + kt + kk;
                av.x = ap[0]; av.y = ap[1]; av.z = ap[2]; av.w = ap[3];
            }
            As[kk + 0][m] = av.x; As[kk + 1][m] = av.y;
            As[kk + 2][m] = av.z; As[kk + 3][m] = av.w;
        }
        {
            int kk = tid >> 4;
            int n  = (tid & 15) * 4;
            int gn = col0 + n;
            const float* bp = B + (size_t)(kt + kk) * N + gn;
            float4 bv = make_float4(0.f, 0.f, 0.f, 0.f);
            if (gn + 3 < N) {
                bv.x = bp[0]; bv.y = bp[1]; bv.z = bp[2]; bv.w = bp[3];
            } else {
                if (gn + 0 < N) bv.x = bp[0];
                if (gn + 1 < N) bv.y = bp[1];
                if (gn + 2 < N) bv.z = bp[2];
                if (gn + 3 < N) bv.w = bp[3];
            }
            Bs[kk][n + 0] = bv.x; Bs[kk][n + 1] = bv.y;
            Bs[kk][n + 2] = bv.z; Bs[kk][n + 3] = bv.w;
        }
        __syncthreads();

        #pragma unroll
        for (int k = 0; k < BK; ++k) {
            float a[4], b[4];
            #pragma unroll
            for (int i = 0; i < 4; ++i) a[i] = As[k][ty * 4 + i];
            #pragma unroll
            for (int j = 0; j < 4; ++j) b[j] = Bs[k][tx * 4 + j];
            #pragma unroll
            for (int i = 0; i < 4; ++i)
                #pragma unroll
                for (int j = 0; j < 4; ++j)
                    c[i][j] += a[i] * b[j];
        }
        __syncthreads();
    }

    #pragma unroll
    for (int i = 0; i < 4; ++i) {
        int gm = row0 + ty * 4 + i;
        if (gm >= M) continue;
        #pragma unroll
        for (int j = 0; j < 4; ++j) {
            int gn = col0 + tx * 4 + j;
            if (gn < N) C[(size_t)gm * N + gn] = c[i][j] + bias[gn];
        }
    }
}

// ---------------------------------------------------------------------------
// Fused softmax + trilinear sampling + head-wise accumulation.
// ---------------------------------------------------------------------------
__global__ __launch_bounds__(128) void sample_kernel(
    const float* __restrict__ refp,
    const float* __restrict__ offb,
    const float* __restrict__ alog,
    const float* __restrict__ vbuf,
    float* __restrict__ attn)
{
    const int q = blockIdx.x;
    const int m = blockIdx.y;
    const int d = threadIdx.x;

    __shared__ float s_off[72];
    __shared__ float s_aw[24];
    __shared__ float s_ref[3];

    if (d < 72) s_off[d] = offb[(size_t)q * OFFC + m * 72 + d];
    if (d < 24) s_aw[d]  = alog[(size_t)q * AWC + m * 24 + d];
    if (d < 3)  s_ref[d] = refp[(size_t)q * 3 + d];
    __syncthreads();

    if (d == 0) {
        float mx = s_aw[0];
        #pragma unroll
        for (int i = 1; i < 24; ++i) mx = fmaxf(mx, s_aw[i]);
        float sum = 0.f;
        #pragma unroll
        for (int i = 0; i < 24; ++i) { float e = expf(s_aw[i] - mx); s_aw[i] = e; sum += e; }
        float inv = 1.f / sum;
        #pragma unroll
        for (int i = 0; i < 24; ++i) s_aw[i] *= inv;
    }
    __syncthreads();

    const int DLS[3]   = {28, 14, 7};
    const int START[3] = {0, 21952, 24696};

    float acc = 0.f;

    #pragma unroll
    for (int t = 0; t < TT; ++t) {
        #pragma unroll
        for (int l = 0; l < LL; ++l) {
            const int   Dl = DLS[l];
            const float fD = (float)Dl;
            const float* vb = vbuf + ((size_t)t * STOT + START[l]) * DMOD + m * DH + d;
            #pragma unroll
            for (int p = 0; p < PP; ++p) {
                const int o = t * 36 + l * 12 + p * 3;
                const float aww = s_aw[t * 12 + l * 4 + p];
                float x = s_ref[0] * fD + s_off[o + 0] - 0.5f;
                float y = s_ref[1] * fD + s_off[o + 1] - 0.5f;
                float z = s_ref[2] * fD + s_off[o + 2] - 0.5f;
                float xf = floorf(x), yf = floorf(y), zf = floorf(z);
                float fx = x - xf, fy = y - yf, fz = z - zf;
                int x0 = (int)xf, y0 = (int)yf, z0 = (int)zf;
                #pragma unroll
                for (int cc = 0; cc < 8; ++cc) {
                    int dx = cc & 1, dy = (cc >> 1) & 1, dz = cc >> 2;
                    int xi = x0 + dx, yi = y0 + dy, zi = z0 + dz;
                    if (xi < 0 || xi >= Dl || yi < 0 || yi >= Dl || zi < 0 || zi >= Dl) continue;
                    float w = (dx ? fx : 1.f - fx) * (dy ? fy : 1.f - fy) * (dz ? fz : 1.f - fz);
                    acc += (aww * w) * vb[(size_t)((zi * Dl + yi) * Dl + xi) * DMOD];
                }
            }
        }
    }

    attn[(size_t)q * DMOD + m * DH + d] = acc;
}

// ---------------------------------------------------------------------------
extern "C" void kernel_launch(void* const* d_in, const int* in_sizes, int n_in,
                              void* d_out, int out_size, void* d_ws, size_t ws_size,
                              hipStream_t stream) {
    const float* query = (const float*)d_in[0];
    const float* refp  = (const float*)d_in[1];
    const float* value = (const float*)d_in[2];
    const float* Wv    = (const float*)d_in[3];
    const float* bv    = (const float*)d_in[4];
    const float* Woff  = (const float*)d_in[5];
    const float* boff  = (const float*)d_in[6];
    const float* Wa    = (const float*)d_in[7];
    const float* ba    = (const float*)d_in[8];
    const float* Wo    = (const float*)d_in[9];
    const float* bo    = (const float*)d_in[10];
    float* out = (float*)d_out;

    // workspace carve-up (floats)
    float* vbuf = (float*)d_ws;                         // 2*25039*768
    float* offb = vbuf + (size_t)TT * STOT * DMOD;      // 4096*432
    float* alog = offb + (size_t)LQ * OFFC;             // 4096*144
    float* attn = alog + (size_t)LQ * AWC;              // 4096*768
    // WvT (bf16, 768*1408 = 2.1 MB) overlaid on attn region: attn is only
    // written by sample_kernel, which runs after G1 has consumed WvT.
    __bf16* wvt = (__bf16*)attn;

    // P0: WvT = transpose(Wv) in bf16
    {
        dim3 grid((IMGD + 31) / 32, (DMOD + 31) / 32);
        cvt_transpose<<<grid, 256, 0, stream>>>(Wv, wvt, IMGD, DMOD);
    }
    // G1: v = value @ Wv + bv     (50078 x 768, K=1408) -- bf16 MFMA
    {
        int M = TT * STOT, N = DMOD, K = IMGD;
        dim3 grid(N / 128, (M + 127) / 128);
        gemm_bf16_mfma<<<grid, 256, 0, stream>>>(value, wvt, bv, vbuf, M, N, K);
    }
    // G2a: off = query @ Woff + boff   (4096 x 432, K=768) -- fp32
    {
        int M = LQ, N = OFFC, K = DMOD;
        dim3 grid((N + BN - 1) / BN, (M + BM - 1) / BM);
        gemm_f32<<<grid, 256, 0, stream>>>(query, Woff, boff, offb, M, N, K);
    }
    // G2b: alog = query @ Wa + ba      (4096 x 144, K=768) -- fp32
    {
        int M = LQ, N = AWC, K = DMOD;
        dim3 grid((N + BN - 1) / BN, (M + BM - 1) / BM);
        gemm_f32<<<grid, 256, 0, stream>>>(query, Wa, ba, alog, M, N, K);
    }
    // sampling + softmax + head accumulation
    {
        dim3 grid(LQ, MM);
        sample_kernel<<<grid, DH, 0, stream>>>(refp, offb, alog, vbuf, attn);
    }
    // G3: out = attn @ Wo + bo         (4096 x 768, K=768) -- fp32
    {
        int M = LQ, N = DMOD, K = DMOD;
        dim3 grid((N + BN - 1) / BN, (M + BM - 1) / BM);
        gemm_f32<<<grid, 256, 0, stream>>>(attn, Wo, bo, out, M, N, K);
    }
}

// Round 3
// 766.099 us; speedup vs baseline: 4.0068x; 1.7611x over previous
//
#include <hip/hip_runtime.h>
#include <hip/hip_bf16.h>
#include <stdint.h>

// Problem constants
#define LQ    4096
#define DMOD  768
#define IMGD  1408
#define TT    2
#define MM    6
#define LL    3
#define PP    4
#define DH    128            // DMOD / MM
#define STOT  25039          // 28^3 + 14^3 + 7^3
#define OFFC  432            // M*T*L*P*3
#define AWC   144            // M*T*L*P
#define PROJC 576            // OFFC + AWC
#define NSAMP 24             // T*L*P
#define NCORN 192            // NSAMP * 8

typedef __attribute__((ext_vector_type(8))) __bf16 bf16x8;
typedef __attribute__((ext_vector_type(4))) float  f32x4;

// async global->LDS, 16B per lane; LDS dest = (wave-uniform) base + lane*16
__device__ __forceinline__ void gl_lds16(const void* g, void* l) {
    __builtin_amdgcn_global_load_lds(
        (const __attribute__((address_space(1))) void*)g,
        (__attribute__((address_space(3))) void*)l, 16, 0, 0);
}

// ---------------------------------------------------------------------------
// Prep: WT[n][k] = (bf16) W[k][n]   (tiled transpose + convert)
// ---------------------------------------------------------------------------
__global__ __launch_bounds__(256) void cvt_transpose(
    const float* __restrict__ W, __bf16* __restrict__ WT, int K, int N)
{
    __shared__ float tile[32][33];
    const int k0 = blockIdx.x * 32, n0 = blockIdx.y * 32;
    const int c = threadIdx.x & 31, r8 = threadIdx.x >> 5;
    #pragma unroll
    for (int i = 0; i < 4; ++i) {
        int r = r8 + i * 8;
        int k = k0 + r, n = n0 + c;
        tile[r][c] = (k < K && n < N) ? W[(size_t)k * N + n] : 0.f;
    }
    __syncthreads();
    #pragma unroll
    for (int i = 0; i < 4; ++i) {
        int r = r8 + i * 8;
        int n = n0 + r, k = k0 + c;
        if (n < N && k < K) WT[(size_t)n * K + k] = (__bf16)tile[c][r];
    }
}

// value f32 -> bf16 (grid-stride, float4 -> 4x bf16)
__global__ __launch_bounds__(256) void cvt_value(
    const float4* __restrict__ src, __bf16* __restrict__ dst, int n4)
{
    int i = blockIdx.x * blockDim.x + threadIdx.x;
    const int stride = gridDim.x * blockDim.x;
    for (; i < n4; i += stride) {
        float4 v = src[i];
        union { __bf16 h[4]; uint64_t u; } pk;
        pk.h[0] = (__bf16)v.x; pk.h[1] = (__bf16)v.y;
        pk.h[2] = (__bf16)v.z; pk.h[3] = (__bf16)v.w;
        *(uint64_t*)(dst + (size_t)i * 4) = pk.u;
    }
}

__global__ void concat_bias(const float* __restrict__ boff,
                            const float* __restrict__ ba,
                            float* __restrict__ bcat)
{
    int i = blockIdx.x * blockDim.x + threadIdx.x;
    if (i < PROJC) bcat[i] = (i < OFFC) ? boff[i] : ba[i - OFFC];
}

// ---------------------------------------------------------------------------
// MFMA GEMM: C(MxN) = A(MxK) @ BT(NxK)^T + bias
// 128x128 tile, BK=32, 4 waves, wave tile 64x64 (4x4 of 16x16x32 bf16 MFMA).
// BT always bf16, staged via global_load_lds(16B). A either bf16 (lds path)
// or f32 (VGPR convert staging). LDS layout [128][32] unpadded (required by
// global_load_lds lane ordering). K%32==0. OOB B rows must be readable
// (guaranteed by ws layout slack); OOB A rows (A_BF16 path) likewise.
// ---------------------------------------------------------------------------
template<bool A_BF16, bool OUT_BF16>
__global__ __launch_bounds__(256) void gemm_mfma(
    const void* __restrict__ Ap, const __bf16* __restrict__ BT,
    const float* __restrict__ bias, void* __restrict__ Cp,
    int M, int N, int K)
{
    __shared__ __bf16 As[128][32];   // 8 KB
    __shared__ __bf16 Bs[128][32];   // 8 KB

    const int tid  = threadIdx.x;
    const int lane = tid & 63;
    const int wave = tid >> 6;
    const int wm = (wave & 1) * 64;
    const int wn = (wave >> 1) * 64;
    const int row0 = blockIdx.y * 128;
    const int col0 = blockIdx.x * 128;
    const int fr = lane & 15;
    const int kq = lane >> 4;

    // A_F32 staging map: thread -> (row, 16-wide k-half)
    const int sr  = tid >> 1;
    const int kk0 = (tid & 1) * 16;

    f32x4 acc[4][4] = {};

    for (int kt = 0; kt < K; kt += 32) {
        // ---- stage B via global_load_lds: 512 chunks of 16B, 2 per wave
        #pragma unroll
        for (int j = 0; j < 2; ++j) {
            const int g   = wave * 128 + j * 64 + lane;   // 16B chunk id
            const int row = g >> 2, cir = g & 3;
            const __bf16* src = BT + (size_t)(col0 + row) * K + kt + cir * 8;
            gl_lds16(src, (char*)&Bs[0][0] + (size_t)(wave * 128 + j * 64) * 16);
        }
        if constexpr (A_BF16) {
            const __bf16* A = (const __bf16*)Ap;
            #pragma unroll
            for (int j = 0; j < 2; ++j) {
                const int g   = wave * 128 + j * 64 + lane;
                const int row = g >> 2, cir = g & 3;
                const __bf16* src = A + (size_t)(row0 + row) * K + kt + cir * 8;
                gl_lds16(src, (char*)&As[0][0] + (size_t)(wave * 128 + j * 64) * 16);
            }
        } else {
            const float* A = (const float*)Ap;
            const int gm = row0 + sr;
            float f[16];
            if (gm < M) {
                const float4* ap = (const float4*)(A + (size_t)gm * K + kt + kk0);
                #pragma unroll
                for (int i = 0; i < 4; ++i) {
                    float4 v = ap[i];
                    f[i*4+0] = v.x; f[i*4+1] = v.y; f[i*4+2] = v.z; f[i*4+3] = v.w;
                }
            } else {
                #pragma unroll
                for (int i = 0; i < 16; ++i) f[i] = 0.f;
            }
            bf16x8 v0, v1;
            #pragma unroll
            for (int i = 0; i < 8; ++i) { v0[i] = (__bf16)f[i]; v1[i] = (__bf16)f[i+8]; }
            *(bf16x8*)&As[sr][kk0]     = v0;
            *(bf16x8*)&As[sr][kk0 + 8] = v1;
        }
        __syncthreads();

        bf16x8 a[4], b[4];
        #pragma unroll
        for (int mt = 0; mt < 4; ++mt) a[mt] = *(const bf16x8*)&As[wm + mt*16 + fr][kq * 8];
        #pragma unroll
        for (int nt = 0; nt < 4; ++nt) b[nt] = *(const bf16x8*)&Bs[wn + nt*16 + fr][kq * 8];
        #pragma unroll
        for (int mt = 0; mt < 4; ++mt)
            #pragma unroll
            for (int nt = 0; nt < 4; ++nt)
                acc[mt][nt] = __builtin_amdgcn_mfma_f32_16x16x32_bf16(
                    a[mt], b[nt], acc[mt][nt], 0, 0, 0);
        __syncthreads();
    }

    // epilogue: C/D layout col=lane&15, row=(lane>>4)*4+reg
    const int col = lane & 15;
    const int rq  = (lane >> 4) * 4;
    #pragma unroll
    for (int mt = 0; mt < 4; ++mt) {
        #pragma unroll
        for (int r = 0; r < 4; ++r) {
            const int gm = row0 + wm + mt*16 + rq + r;
            if (gm >= M) continue;
            #pragma unroll
            for (int nt = 0; nt < 4; ++nt) {
                const int gn = col0 + wn + nt*16 + col;
                if (gn < N) {
                    float v = acc[mt][nt][r] + bias[gn];
                    if constexpr (OUT_BF16)
                        ((__bf16*)Cp)[(size_t)gm * N + gn] = (__bf16)v;
                    else
                        ((float*)Cp)[(size_t)gm * N + gn] = v;
                }
            }
        }
    }
}

// ---------------------------------------------------------------------------
// Fused softmax + trilinear sampling. One wave per (q, m); 4 waves/block.
// Lane handles 2 channels (one 4B bf16x2 gather per corner).
// Phase 1: lanes 0..23 precompute 192 (weight, byte-offset) pairs into LDS.
// Phase 2: tight broadcast-read + gather + FMA loop.
// ---------------------------------------------------------------------------
__global__ __launch_bounds__(256) void sample_kernel(
    const float* __restrict__ refp,   // (LQ,3)
    const float* __restrict__ proj,   // (LQ,576): [0,432)=off, [432,576)=logits
    const __bf16* __restrict__ vbuf,  // (T,STOT,768) bf16
    __bf16* __restrict__ attn)        // (LQ,768) bf16
{
    const int wave = threadIdx.x >> 6;
    const int lane = threadIdx.x & 63;
    const int q = blockIdx.x * 4 + wave;
    const int m = blockIdx.y;

    __shared__ float    s_aw[4][NSAMP];
    __shared__ float    s_w[4][NCORN];
    __shared__ uint32_t s_o[4][NCORN];

    if (lane < NSAMP)
        s_aw[wave][lane] = proj[(size_t)q * PROJC + OFFC + m * NSAMP + lane];
    __syncthreads();

    if (lane < NSAMP) {
        // softmax weight for this lane's sample (redundant max/sum, 24 lanes)
        float mx = -1e30f;
        #pragma unroll
        for (int i = 0; i < NSAMP; ++i) mx = fmaxf(mx, s_aw[wave][i]);
        float sum = 0.f;
        #pragma unroll
        for (int i = 0; i < NSAMP; ++i) sum += __expf(s_aw[wave][i] - mx);
        const float aww = __expf(s_aw[wave][lane] - mx) / sum;

        // lane = t*12 + l*4 + p
        const int t = lane / 12;
        const int r = lane - t * 12;
        const int l = r >> 2;
        const int   Dl    = (l == 0) ? 28 : (l == 1) ? 14 : 7;
        const int   start = (l == 0) ? 0  : (l == 1) ? 21952 : 24696;
        const float fD    = (float)Dl;
        const int   base  = t * STOT + start;

        const float* op = proj + (size_t)q * PROJC + m * 72 + lane * 3;
        const float rx = refp[q*3+0], ry = refp[q*3+1], rz = refp[q*3+2];
        float x = rx * fD + op[0] - 0.5f;
        float y = ry * fD + op[1] - 0.5f;
        float z = rz * fD + op[2] - 0.5f;
        float xf = floorf(x), yf = floorf(y), zf = floorf(z);
        float fx = x - xf, fy = y - yf, fz = z - zf;
        int x0 = (int)xf, y0 = (int)yf, z0 = (int)zf;
        float wx[2] = {1.f - fx, fx}, wy[2] = {1.f - fy, fy}, wz[2] = {1.f - fz, fz};
        #pragma unroll
        for (int cc = 0; cc < 8; ++cc) {
            int dx = cc & 1, dy = (cc >> 1) & 1, dz = cc >> 2;
            int xi = x0 + dx, yi = y0 + dy, zi = z0 + dz;
            bool ok = (xi >= 0) & (xi < Dl) & (yi >= 0) & (yi < Dl) &
                      (zi >= 0) & (zi < Dl);
            float    w   = ok ? aww * wx[dx] * wy[dy] * wz[dz] : 0.f;
            uint32_t off = ok ? (uint32_t)(base + (zi * Dl + yi) * Dl + xi) * (768u * 2u) : 0u;
            s_w[wave][lane * 8 + cc] = w;
            s_o[wave][lane * 8 + cc] = off;
        }
    }
    __syncthreads();

    const char* vb = (const char*)vbuf + ((size_t)m * 128 + lane * 2) * 2;
    float acc0 = 0.f, acc1 = 0.f;
    #pragma unroll 8
    for (int i = 0; i < NCORN; ++i) {
        const float    w   = s_w[wave][i];   // LDS broadcast
        const uint32_t off = s_o[wave][i];   // LDS broadcast
        const uint32_t u = *(const uint32_t*)(vb + off);
        acc0 += w * __uint_as_float(u << 16);
        acc1 += w * __uint_as_float(u & 0xffff0000u);
    }

    union { __bf16 h[2]; uint32_t u; } pk;
    pk.h[0] = (__bf16)acc0; pk.h[1] = (__bf16)acc1;
    *(uint32_t*)((char*)attn + ((size_t)q * DMOD + m * 128 + lane * 2) * 2) = pk.u;
}

// ---------------------------------------------------------------------------
extern "C" void kernel_launch(void* const* d_in, const int* in_sizes, int n_in,
                              void* d_out, int out_size, void* d_ws, size_t ws_size,
                              hipStream_t stream) {
    const float* query = (const float*)d_in[0];
    const float* refp  = (const float*)d_in[1];
    const float* value = (const float*)d_in[2];
    const float* Wv    = (const float*)d_in[3];
    const float* bv    = (const float*)d_in[4];
    const float* Woff  = (const float*)d_in[5];
    const float* boff  = (const float*)d_in[6];
    const float* Wa    = (const float*)d_in[7];
    const float* ba    = (const float*)d_in[8];
    const float* Wo    = (const float*)d_in[9];
    const float* bo    = (const float*)d_in[10];
    float* out = (float*)d_out;

    const size_t SZ_VALBF = (size_t)TT * STOT * IMGD * 2;   // 141,019,648
    const size_t SZ_VBUF  = (size_t)TT * STOT * DMOD * 2;   //  76,919,808
    const size_t SZ_PROJ  = (size_t)LQ * PROJC * 4;         //   9,437,184
    const size_t SZ_ATTN  = (size_t)LQ * DMOD * 2;          //   6,291,456
    const size_t SZ_WVT   = (size_t)IMGD * DMOD * 2;        //   2,162,688
    const size_t SZ_WCAT  = (size_t)PROJC * DMOD * 2;       //     884,736
    const size_t SZ_WOT   = (size_t)DMOD * DMOD * 2;        //   1,179,648
    const size_t NEED_FAST = SZ_VALBF + SZ_VBUF + SZ_PROJ + SZ_ATTN +
                             SZ_WVT + SZ_WCAT + SZ_WOT + 8192;
    const bool fast = ws_size >= NEED_FAST;

    char* p = (char*)d_ws;
    __bf16* valbf = nullptr;
    if (fast) { valbf = (__bf16*)p; p += SZ_VALBF; }
    __bf16* vbuf  = (__bf16*)p; p += SZ_VBUF;
    float*  proj  = (float*)p;  p += SZ_PROJ;
    __bf16* attn  = (__bf16*)p; p += SZ_ATTN;
    __bf16* wvt   = (__bf16*)p; p += SZ_WVT;
    __bf16* wcatT = (__bf16*)p; p += SZ_WCAT;
    __bf16* woT   = (__bf16*)p; p += SZ_WOT;
    float*  bcat  = (float*)p;

    // ---- weight preps
    cvt_transpose<<<dim3((IMGD+31)/32, (DMOD+31)/32), 256, 0, stream>>>(Wv, wvt, IMGD, DMOD);
    cvt_transpose<<<dim3((DMOD+31)/32, (OFFC+31)/32), 256, 0, stream>>>(Woff, wcatT, DMOD, OFFC);
    cvt_transpose<<<dim3((DMOD+31)/32, (AWC +31)/32), 256, 0, stream>>>(Wa, wcatT + (size_t)OFFC * DMOD, DMOD, AWC);
    cvt_transpose<<<dim3((DMOD+31)/32, (DMOD+31)/32), 256, 0, stream>>>(Wo, woT, DMOD, DMOD);
    concat_bias<<<dim3(3), 256, 0, stream>>>(boff, ba, bcat);

    const int Mv = TT * STOT;   // 50078

    // ---- G1: vbuf = value @ Wv + bv  (bf16 out)
    if (fast) {
        cvt_value<<<dim3(4096), 256, 0, stream>>>((const float4*)value, valbf,
                                                  (int)((size_t)TT * STOT * IMGD / 4));
        gemm_mfma<true, true><<<dim3(DMOD/128, (Mv+127)/128), 256, 0, stream>>>(
            valbf, wvt, bv, vbuf, Mv, DMOD, IMGD);
    } else {
        gemm_mfma<false, true><<<dim3(DMOD/128, (Mv+127)/128), 256, 0, stream>>>(
            value, wvt, bv, vbuf, Mv, DMOD, IMGD);
    }

    // ---- G2: proj = query @ [Woff|Wa] + [boff|ba]  (f32 out)
    gemm_mfma<false, false><<<dim3((PROJC+127)/128, LQ/128), 256, 0, stream>>>(
        query, wcatT, bcat, proj, LQ, PROJC, DMOD);

    // ---- sampling + softmax + head accumulation (bf16 out)
    sample_kernel<<<dim3(LQ/4, MM), 256, 0, stream>>>(refp, proj, vbuf, attn);

    // ---- G3: out = attn @ Wo + bo  (f32 out)
    gemm_mfma<true, false><<<dim3(DMOD/128, LQ/128), 256, 0, stream>>>(
        attn, woT, bo, out, LQ, DMOD, DMOD);
}

// Round 4
// 731.678 us; speedup vs baseline: 4.1953x; 1.0470x over previous
//
#include <hip/hip_runtime.h>
#include <hip/hip_bf16.h>
#include <stdint.h>

// Problem constants
#define LQ    4096
#define DMOD  768
#define IMGD  1408
#define TT    2
#define MM    6
#define LL    3
#define PP    4
#define DH    128
#define STOT  25039          // 28^3 + 14^3 + 7^3
#define OFFC  432
#define AWC   144
#define PROJC 576
#define NSAMP 24
#define NCORN 192

typedef __attribute__((ext_vector_type(8))) __bf16 bf16x8;
typedef __attribute__((ext_vector_type(4))) float  f32x4;

__device__ __forceinline__ void gl_lds16(const void* g, void* l) {
    __builtin_amdgcn_global_load_lds(
        (const __attribute__((address_space(1))) void*)g,
        (__attribute__((address_space(3))) void*)l, 16, 0, 0);
}

// ---------------------------------------------------------------------------
// Prep: WT[n][k] = (bf16) W[k][n]
// ---------------------------------------------------------------------------
__global__ __launch_bounds__(256) void cvt_transpose(
    const float* __restrict__ W, __bf16* __restrict__ WT, int K, int N)
{
    __shared__ float tile[32][33];
    const int k0 = blockIdx.x * 32, n0 = blockIdx.y * 32;
    const int c = threadIdx.x & 31, r8 = threadIdx.x >> 5;
    #pragma unroll
    for (int i = 0; i < 4; ++i) {
        int r = r8 + i * 8;
        int k = k0 + r, n = n0 + c;
        tile[r][c] = (k < K && n < N) ? W[(size_t)k * N + n] : 0.f;
    }
    __syncthreads();
    #pragma unroll
    for (int i = 0; i < 4; ++i) {
        int r = r8 + i * 8;
        int n = n0 + r, k = k0 + c;
        if (n < N && k < K) WT[(size_t)n * K + k] = (__bf16)tile[c][r];
    }
}

__global__ void concat_bias(const float* __restrict__ boff,
                            const float* __restrict__ ba,
                            float* __restrict__ bcat)
{
    int i = blockIdx.x * blockDim.x + threadIdx.x;
    if (i < PROJC) bcat[i] = (i < OFFC) ? boff[i] : ba[i - OFFC];
}

// ---------------------------------------------------------------------------
// MFMA GEMM, double-buffered single-barrier K-loop.
// C(MxN) = A(MxK) @ BT(NxK)^T + bias
// 128x128 tile, BK=32, 4 waves, wave 64x64 (4x4 of 16x16x32 bf16 MFMA).
// AF32=1: A is f32, converted in VGPRs during staging (ds_write path).
// AF32=0: A is bf16, staged via global_load_lds (rows must be in-bounds).
// SWZ>0: 1-D grid; 6 N-blocks of each M-panel co-located on one XCD.
// B rows beyond N must be readable (ws layout guarantees slack).
// ---------------------------------------------------------------------------
template<int AF32, int OUT_BF16, int SWZ>
__global__ __launch_bounds__(256, 3) void gemm_mfma(
    const void* __restrict__ Ap, const __bf16* __restrict__ BT,
    const float* __restrict__ bias, void* __restrict__ Cp,
    int M, int N, int K)
{
    __shared__ __bf16 As[2][128][32];   // 16 KB
    __shared__ __bf16 Bs[2][128][32];   // 16 KB

    const int tid  = threadIdx.x;
    const int lane = tid & 63;
    const int wave = tid >> 6;
    const int wm = (wave & 1) * 64;
    const int wn = (wave >> 1) * 64;

    int bx, by;
    if constexpr (SWZ > 0) {
        const int bid = blockIdx.x;
        const int xcd = bid & 7;
        const int slot = bid >> 3;
        const int ppx = (gridDim.x >> 3) / SWZ;   // panels per XCD
        const int pix = slot / SWZ;
        bx = slot - pix * SWZ;
        by = xcd * ppx + pix;
    } else {
        bx = blockIdx.x; by = blockIdx.y;
    }
    const int row0 = by * 128;
    const int col0 = bx * 128;

    const int fr = lane & 15;
    const int kq = lane >> 4;

    // staging maps
    const int sr  = tid >> 1;          // AF32: row
    const int kk0 = (tid & 1) * 16;    // AF32: k-half
    const int gB_row = (wave * 128 + lane) >> 2;      // reused pattern base
    (void)gB_row;

    float f[16];

    // ---- helpers inlined via lambdas
    auto stageB = [&](int ki, int buf) {
        #pragma unroll
        for (int j = 0; j < 2; ++j) {
            const int g   = wave * 128 + j * 64 + lane;
            const int row = g >> 2, cir = g & 3;
            const __bf16* src = BT + (size_t)(col0 + row) * K + ki * 32 + cir * 8;
            gl_lds16(src, (char*)&Bs[buf][0][0] + (size_t)(wave * 128 + j * 64) * 16);
        }
    };
    auto stageA_lds = [&](int ki, int buf) {
        const __bf16* A = (const __bf16*)Ap;
        #pragma unroll
        for (int j = 0; j < 2; ++j) {
            const int g   = wave * 128 + j * 64 + lane;
            const int row = g >> 2, cir = g & 3;
            const __bf16* src = A + (size_t)(row0 + row) * K + ki * 32 + cir * 8;
            gl_lds16(src, (char*)&As[buf][0][0] + (size_t)(wave * 128 + j * 64) * 16);
        }
    };
    auto loadA_f32 = [&](int ki) {
        const float* A = (const float*)Ap;
        const int gm = row0 + sr;
        if (gm < M) {
            const float4* ap = (const float4*)(A + (size_t)gm * K + ki * 32 + kk0);
            #pragma unroll
            for (int i = 0; i < 4; ++i) {
                float4 v = ap[i];
                f[i*4+0] = v.x; f[i*4+1] = v.y; f[i*4+2] = v.z; f[i*4+3] = v.w;
            }
        } else {
            #pragma unroll
            for (int i = 0; i < 16; ++i) f[i] = 0.f;
        }
    };
    auto writeA = [&](int buf) {
        bf16x8 v0, v1;
        #pragma unroll
        for (int i = 0; i < 8; ++i) { v0[i] = (__bf16)f[i]; v1[i] = (__bf16)f[i+8]; }
        *(bf16x8*)&As[buf][sr][kk0]     = v0;
        *(bf16x8*)&As[buf][sr][kk0 + 8] = v1;
    };

    f32x4 acc[4][4] = {};
    const int nk = K >> 5;

    // ---- prologue: stage tile 0 into buffer 0
    stageB(0, 0);
    if constexpr (AF32) { loadA_f32(0); writeA(0); }
    else                { stageA_lds(0, 0); }

    for (int i = 0; i < nk; ++i) {
        __syncthreads();   // publishes buf cur (compiler drains vmcnt/lgkmcnt)
        const int cur = i & 1, nxt = cur ^ 1;
        const bool more = (i + 1) < nk;

        if (more) {
            stageB(i + 1, nxt);
            if constexpr (AF32) loadA_f32(i + 1);
            else                stageA_lds(i + 1, nxt);
        }

        bf16x8 a[4], b[4];
        #pragma unroll
        for (int mt = 0; mt < 4; ++mt) a[mt] = *(const bf16x8*)&As[cur][wm + mt*16 + fr][kq * 8];
        #pragma unroll
        for (int nt = 0; nt < 4; ++nt) b[nt] = *(const bf16x8*)&Bs[cur][wn + nt*16 + fr][kq * 8];
        #pragma unroll
        for (int mt = 0; mt < 4; ++mt)
            #pragma unroll
            for (int nt = 0; nt < 4; ++nt)
                acc[mt][nt] = __builtin_amdgcn_mfma_f32_16x16x32_bf16(
                    a[mt], b[nt], acc[mt][nt], 0, 0, 0);

        if constexpr (AF32) { if (more) writeA(nxt); }
    }

    // ---- epilogue: C/D layout col=lane&15, row=(lane>>4)*4+reg
    const int col = lane & 15;
    const int rq  = (lane >> 4) * 4;
    #pragma unroll
    for (int mt = 0; mt < 4; ++mt) {
        #pragma unroll
        for (int r = 0; r < 4; ++r) {
            const int gm = row0 + wm + mt*16 + rq + r;
            if (gm >= M) continue;
            #pragma unroll
            for (int nt = 0; nt < 4; ++nt) {
                const int gn = col0 + wn + nt*16 + col;
                if (gn < N) {
                    float v = acc[mt][nt][r] + bias[gn];
                    if constexpr (OUT_BF16)
                        ((__bf16*)Cp)[(size_t)gm * N + gn] = (__bf16)v;
                    else
                        ((float*)Cp)[(size_t)gm * N + gn] = v;
                }
            }
        }
    }
}

// ---------------------------------------------------------------------------
// Fused softmax + trilinear sampling. One wave per (q, m); 4 waves/block.
// Lane = (h = corner parity, c = channel quad): uint2 gather (4 channels).
// ---------------------------------------------------------------------------
__global__ __launch_bounds__(256) void sample_kernel(
    const float* __restrict__ refp,   // (LQ,3)
    const float* __restrict__ proj,   // (LQ,576): [0,432)=off, [432,576)=logits
    const __bf16* __restrict__ vbuf,  // (T,STOT,768) bf16
    __bf16* __restrict__ attn)        // (LQ,768) bf16
{
    const int wave = threadIdx.x >> 6;
    const int lane = threadIdx.x & 63;
    const int q = blockIdx.x * 4 + wave;
    const int m = blockIdx.y;

    __shared__ float    s_aw[4][NSAMP];
    __shared__ float    s_w[4][NCORN];
    __shared__ uint32_t s_o[4][NCORN];

    if (lane < NSAMP)
        s_aw[wave][lane] = proj[(size_t)q * PROJC + OFFC + m * NSAMP + lane];
    __syncthreads();

    if (lane < NSAMP) {
        float mx = -1e30f;
        #pragma unroll
        for (int i = 0; i < NSAMP; ++i) mx = fmaxf(mx, s_aw[wave][i]);
        float sum = 0.f;
        #pragma unroll
        for (int i = 0; i < NSAMP; ++i) sum += __expf(s_aw[wave][i] - mx);
        const float aww = __expf(s_aw[wave][lane] - mx) / sum;

        const int t = lane / 12;
        const int r = lane - t * 12;
        const int l = r >> 2;
        const int   Dl    = (l == 0) ? 28 : (l == 1) ? 14 : 7;
        const int   start = (l == 0) ? 0  : (l == 1) ? 21952 : 24696;
        const float fD    = (float)Dl;
        const int   base  = t * STOT + start;

        const float* op = proj + (size_t)q * PROJC + m * 72 + lane * 3;
        const float rx = refp[q*3+0], ry = refp[q*3+1], rz = refp[q*3+2];
        float x = rx * fD + op[0] - 0.5f;
        float y = ry * fD + op[1] - 0.5f;
        float z = rz * fD + op[2] - 0.5f;
        float xf = floorf(x), yf = floorf(y), zf = floorf(z);
        float fx = x - xf, fy = y - yf, fz = z - zf;
        int x0 = (int)xf, y0 = (int)yf, z0 = (int)zf;
        float wx[2] = {1.f - fx, fx}, wy[2] = {1.f - fy, fy}, wz[2] = {1.f - fz, fz};
        #pragma unroll
        for (int cc = 0; cc < 8; ++cc) {
            int dx = cc & 1, dy = (cc >> 1) & 1, dz = cc >> 2;
            int xi = x0 + dx, yi = y0 + dy, zi = z0 + dz;
            bool ok = (xi >= 0) & (xi < Dl) & (yi >= 0) & (yi < Dl) &
                      (zi >= 0) & (zi < Dl);
            float    w   = ok ? aww * wx[dx] * wy[dy] * wz[dz] : 0.f;
            uint32_t off = ok ? (uint32_t)(base + (zi * Dl + yi) * Dl + xi) * (768u * 2u) : 0u;
            s_w[wave][lane * 8 + cc] = w;
            s_o[wave][lane * 8 + cc] = off;
        }
    }
    __syncthreads();

    const int h = lane >> 5;          // corner parity
    const int c = lane & 31;          // channel quad
    const char* vb = (const char*)vbuf + ((size_t)m * 128 + c * 4) * 2;
    float a0 = 0.f, a1 = 0.f, a2 = 0.f, a3 = 0.f;
    #pragma unroll 4
    for (int i = 0; i < NCORN / 2; ++i) {
        const float    w   = s_w[wave][2 * i + h];
        const uint32_t off = s_o[wave][2 * i + h];
        const uint2 u = *(const uint2*)(vb + off);
        a0 += w * __uint_as_float(u.x << 16);
        a1 += w * __uint_as_float(u.x & 0xffff0000u);
        a2 += w * __uint_as_float(u.y << 16);
        a3 += w * __uint_as_float(u.y & 0xffff0000u);
    }
    a0 += __shfl_xor(a0, 32);
    a1 += __shfl_xor(a1, 32);
    a2 += __shfl_xor(a2, 32);
    a3 += __shfl_xor(a3, 32);

    if (h == 0) {
        union { __bf16 hh[4]; uint2 u; } pk;
        pk.hh[0] = (__bf16)a0; pk.hh[1] = (__bf16)a1;
        pk.hh[2] = (__bf16)a2; pk.hh[3] = (__bf16)a3;
        *(uint2*)((char*)attn + ((size_t)q * DMOD + m * 128 + c * 4) * 2) = pk.u;
    }
}

// ---------------------------------------------------------------------------
extern "C" void kernel_launch(void* const* d_in, const int* in_sizes, int n_in,
                              void* d_out, int out_size, void* d_ws, size_t ws_size,
                              hipStream_t stream) {
    const float* query = (const float*)d_in[0];
    const float* refp  = (const float*)d_in[1];
    const float* value = (const float*)d_in[2];
    const float* Wv    = (const float*)d_in[3];
    const float* bv    = (const float*)d_in[4];
    const float* Woff  = (const float*)d_in[5];
    const float* boff  = (const float*)d_in[6];
    const float* Wa    = (const float*)d_in[7];
    const float* ba    = (const float*)d_in[8];
    const float* Wo    = (const float*)d_in[9];
    const float* bo    = (const float*)d_in[10];
    float* out = (float*)d_out;

    const size_t SZ_VBUF = (size_t)TT * STOT * DMOD * 2;   // 76,919,808
    const size_t SZ_PROJ = (size_t)LQ * PROJC * 4;         //  9,437,184
    const size_t SZ_ATTN = (size_t)LQ * DMOD * 2;          //  6,291,456
    const size_t SZ_WVT  = (size_t)IMGD * DMOD * 2;        //  2,162,688
    const size_t SZ_WCAT = (size_t)PROJC * DMOD * 2;       //    884,736
    const size_t SZ_WOT  = (size_t)DMOD * DMOD * 2;        //  1,179,648

    char* p = (char*)d_ws;
    __bf16* vbuf  = (__bf16*)p; p += SZ_VBUF;
    float*  proj  = (float*)p;  p += SZ_PROJ;
    __bf16* attn  = (__bf16*)p; p += SZ_ATTN;
    __bf16* wvt   = (__bf16*)p; p += SZ_WVT;
    __bf16* wcatT = (__bf16*)p; p += SZ_WCAT;   // OOB B-rows spill into woT: readable
    __bf16* woT   = (__bf16*)p; p += SZ_WOT;
    float*  bcat  = (float*)p;

    // ---- weight preps
    cvt_transpose<<<dim3((IMGD+31)/32, (DMOD+31)/32), 256, 0, stream>>>(Wv, wvt, IMGD, DMOD);
    cvt_transpose<<<dim3((DMOD+31)/32, (OFFC+31)/32), 256, 0, stream>>>(Woff, wcatT, DMOD, OFFC);
    cvt_transpose<<<dim3((DMOD+31)/32, (AWC +31)/32), 256, 0, stream>>>(Wa, wcatT + (size_t)OFFC * DMOD, DMOD, AWC);
    cvt_transpose<<<dim3((DMOD+31)/32, (DMOD+31)/32), 256, 0, stream>>>(Wo, woT, DMOD, DMOD);
    concat_bias<<<dim3(3), 256, 0, stream>>>(boff, ba, bcat);

    const int Mv = TT * STOT;   // 50078

    // ---- G1: vbuf = value @ Wv + bv (f32 A converted in staging; bf16 out)
    // grid = 392 panels x 6 cols = 2352 = 8 XCDs x 49 panels x 6 cols
    gemm_mfma<1, 1, 6><<<dim3(2352), 256, 0, stream>>>(
        value, wvt, bv, vbuf, Mv, DMOD, IMGD);

    // ---- G2: proj = query @ [Woff|Wa] + [boff|ba]  (f32 out)
    gemm_mfma<1, 0, 0><<<dim3((PROJC + 127) / 128, LQ / 128), 256, 0, stream>>>(
        query, wcatT, bcat, proj, LQ, PROJC, DMOD);

    // ---- sampling + softmax + head accumulation (bf16 out)
    sample_kernel<<<dim3(LQ / 4, MM), 256, 0, stream>>>(refp, proj, vbuf, attn);

    // ---- G3: out = attn @ Wo + bo  (bf16 A via lds path; f32 out)
    gemm_mfma<0, 0, 0><<<dim3(DMOD / 128, LQ / 128), 256, 0, stream>>>(
        attn, woT, bo, out, LQ, DMOD, DMOD);
}